// Round 9
// baseline (641.705 us; speedup 1.0000x reference)
//
#include <hip/hip_runtime.h>

typedef __attribute__((ext_vector_type(8))) short short8;
typedef __attribute__((ext_vector_type(4))) float f32x4;

constexpr int B_ = 4, S_ = 2048, E_ = 1024, H_ = 8, D_ = 256;
constexpr int HD_ = H_ * D_;   // 2048
constexpr int BS_ = B_ * S_;   // 8192
constexpr int BH_ = B_ * H_;   // 32
constexpr float C1_ = 0.04508422002778011f;  // log2(e)/sqrt(1024)
constexpr float LOG2E_ = 1.4426950408889634f;

__device__ __forceinline__ unsigned short f2bf(float f) {
    union { float f; unsigned u; } x; x.f = f;
    unsigned r = (x.u + 0x7fffu + ((x.u >> 16) & 1u)) >> 16;
    return (unsigned short)r;
}

__device__ __forceinline__ unsigned pk2(float a, float b) {
    return (unsigned)f2bf(a) | ((unsigned)f2bf(b) << 16);
}

__device__ __forceinline__ void gl_lds16(const void* g, void* lds) {
    __builtin_amdgcn_global_load_lds((const __attribute__((address_space(1))) void*)g,
                                     (__attribute__((address_space(3))) void*)lds, 16, 0, 0);
}

// ---------------- cast A fp32 -> bf16 (vectorized) ----------------
__global__ __launch_bounds__(256) void cast_k(const float* __restrict__ src,
                                              unsigned short* __restrict__ dst, int n4) {
    int i = blockIdx.x * 256 + threadIdx.x;
    if (i >= n4) return;
    float4 v = reinterpret_cast<const float4*>(src)[i];
    ushort4 o;
    o.x = f2bf(v.x); o.y = f2bf(v.y); o.z = f2bf(v.z); o.w = f2bf(v.w);
    reinterpret_cast<ushort4*>(dst)[i] = o;
}

// ------------- batched transpose+cast: (bt,R,C) f32 -> (bt,C,R) bf16 -------------
__global__ __launch_bounds__(256) void tcast_k(const float* __restrict__ src,
                                               unsigned short* __restrict__ dst, int R, int C) {
    __shared__ float tile[32][33];
    int b = blockIdx.z;
    const float* s = src + (size_t)b * R * C;
    unsigned short* d = dst + (size_t)b * R * C;
    int c0 = blockIdx.x * 32, r0 = blockIdx.y * 32;
    int tx = threadIdx.x, ty = threadIdx.y;
#pragma unroll
    for (int i = 0; i < 4; ++i)
        tile[ty + i * 8][tx] = s[(size_t)(r0 + ty + i * 8) * C + c0 + tx];
    __syncthreads();
#pragma unroll
    for (int i = 0; i < 4; ++i)
        d[(size_t)(c0 + ty + i * 8) * R + r0 + tx] = f2bf(tile[tx][ty + i * 8]);
}

// ------------- bf16 transpose: (BH,S,D) -> (BH,D,S) -------------
__global__ __launch_bounds__(256) void tbf_k(const unsigned short* __restrict__ src,
                                             unsigned short* __restrict__ dst) {
    __shared__ unsigned short tile[32][33];
    int bh = blockIdx.z;
    int d0 = blockIdx.x * 32, s0 = blockIdx.y * 32;
    int tx = threadIdx.x, ty = threadIdx.y;
#pragma unroll
    for (int i = 0; i < 4; ++i)
        tile[ty + i * 8][tx] = src[((size_t)bh * S_ + s0 + ty + i * 8) * D_ + d0 + tx];
    __syncthreads();
#pragma unroll
    for (int i = 0; i < 4; ++i)
        dst[((size_t)bh * D_ + d0 + ty + i * 8) * S_ + s0 + tx] = tile[tx][ty + i * 8];
}

// ======== gemm_qkv256_k: 256x256 tile, BK=64, 2-phase single-barrier pipeline.
// (r8-proven) ========
__global__ __launch_bounds__(512, 2) void gemm_qkv256_k(const unsigned short* __restrict__ A,
                                                        const unsigned short* __restrict__ Bt,
                                                        const float* __restrict__ bias,
                                                        unsigned short* __restrict__ out) {
    __shared__ __align__(16) unsigned short As[2][256 * 64];  // 64 KB
    __shared__ __align__(16) unsigned short Bs[2][256 * 64];  // 64 KB
    const int tid = threadIdx.x;
    const int wave = tid >> 6, lane = tid & 63;
    const int quad = lane >> 4, l15 = lane & 15;
    const int wm = wave >> 2, wn = wave & 3;
    const int lrow = lane >> 3, lc = lane & 7;
    const int p = blockIdx.x;
    const int n0 = (p & 7) * 256;          // XCD-locked B panel
    const int m0 = (p >> 3) * 256;
    int aoff[4], boff[4];
#pragma unroll
    for (int i = 0; i < 4; ++i) {
        int rA = m0 + (wave * 4 + i) * 8 + lrow;
        int rB = n0 + (wave * 4 + i) * 8 + lrow;
        aoff[i] = rA * E_ + (lc ^ lrow) * 8;
        boff[i] = rB * E_ + (lc ^ lrow) * 8;
    }
    f32x4 acc[8][4] = {};
#pragma unroll
    for (int i = 0; i < 4; ++i) {
        gl_lds16(A + aoff[i], (char*)As + (wave * 4 + i) * 1024);
        gl_lds16(Bt + boff[i], (char*)Bs + (wave * 4 + i) * 1024);
    }
    __syncthreads();
    const int v0 = (quad ^ (l15 & 7)) * 16;
    const int arow = (wm * 128 + l15) * 128;
    const int brow = (wn * 64 + l15) * 128;
    for (int k0 = 0; k0 < E_; k0 += 64) {
        const int cur = (k0 >> 6) & 1;
        if (k0 + 64 < E_) {
            char* An = (char*)As + (cur ^ 1) * 32768;
            char* Bn = (char*)Bs + (cur ^ 1) * 32768;
#pragma unroll
            for (int i = 0; i < 4; ++i) {
                gl_lds16(A + aoff[i] + k0 + 64, An + (wave * 4 + i) * 1024);
                gl_lds16(Bt + boff[i] + k0 + 64, Bn + (wave * 4 + i) * 1024);
            }
        }
        const char* Ac = (const char*)As + cur * 32768;
        const char* Bc = (const char*)Bs + cur * 32768;
#pragma unroll
        for (int kcc = 0; kcc < 2; ++kcc) {
            const int vk = v0 ^ (kcc << 6);
            short8 af[8], bf[4];
#pragma unroll
            for (int fm = 0; fm < 8; ++fm)
                af[fm] = *(const short8*)(Ac + arow + fm * 2048 + vk);
#pragma unroll
            for (int fn = 0; fn < 4; ++fn)
                bf[fn] = *(const short8*)(Bc + brow + fn * 2048 + vk);
#pragma unroll
            for (int fm = 0; fm < 8; ++fm)
#pragma unroll
                for (int fn = 0; fn < 4; ++fn)
                    acc[fm][fn] = __builtin_amdgcn_mfma_f32_16x16x32_bf16(af[fm], bf[fn], acc[fm][fn], 0, 0, 0);
        }
        __syncthreads();
    }
#pragma unroll
    for (int fm = 0; fm < 8; ++fm) {
        int mbase = m0 + wm * 128 + fm * 16 + quad * 4;
#pragma unroll
        for (int fn = 0; fn < 4; ++fn) {
            int n = n0 + wn * 64 + fn * 16 + l15;
            int h = n >> 8, d = n & 255;
            float bv = bias[n];
#pragma unroll
            for (int r = 0; r < 4; ++r) {
                int m = mbase + r;
                int b = m >> 11, s = m & 2047;
                float v = fmaxf(acc[fm][fn][r] + bv, 0.0f);
                out[((size_t)(b * H_ + h) * S_ + s) * D_ + d] = f2bf(v);
            }
        }
    }
}

// ------------- output GEMM: Zall(BS,HD) x Wzt(n)[k] + bZ -> fp32 (BS,E) -------------
__global__ __launch_bounds__(256) void gemm_out_k(const unsigned short* __restrict__ A,
                                                  const unsigned short* __restrict__ Bt,
                                                  const float* __restrict__ bias,
                                                  float* __restrict__ out) {
    __shared__ __align__(16) unsigned short As[128 * 32];
    __shared__ __align__(16) unsigned short Bs[128 * 32];
    const int tid = threadIdx.x;
    const int wave = tid >> 6, lane = tid & 63;
    const int quad = lane >> 4, l15 = lane & 15;
    const int wm = wave >> 1, wn = wave & 1;
    const int m0 = blockIdx.y * 128, n0 = blockIdx.x * 128;
    const int c1 = tid, c2 = tid + 256;
    const int r1 = c1 >> 2, kc1 = (c1 & 3) * 8;
    const int r2 = c2 >> 2, kc2 = (c2 & 3) * 8;
    char* aB1 = (char*)As + wave * 1024; char* aB2 = aB1 + 4096;
    char* bB1 = (char*)Bs + wave * 1024; char* bB2 = bB1 + 4096;
    const unsigned short* a1 = A + (size_t)(m0 + r1) * HD_ + kc1;
    const unsigned short* a2 = A + (size_t)(m0 + r2) * HD_ + kc2;
    const unsigned short* b1 = Bt + (size_t)(n0 + r1) * HD_ + kc1;
    const unsigned short* b2 = Bt + (size_t)(n0 + r2) * HD_ + kc2;
    f32x4 acc[4][4] = {};
    for (int k0 = 0; k0 < HD_; k0 += 32) {
        __syncthreads();
        gl_lds16(a1 + k0, aB1);
        gl_lds16(a2 + k0, aB2);
        gl_lds16(b1 + k0, bB1);
        gl_lds16(b2 + k0, bB2);
        __syncthreads();
        short8 af[4], bf[4];
        const short* Ass = (const short*)As;
        const short* Bss = (const short*)Bs;
#pragma unroll
        for (int f = 0; f < 4; ++f) {
            af[f] = *(const short8*)&Ass[(wm * 64 + f * 16 + l15) * 32 + quad * 8];
            bf[f] = *(const short8*)&Bss[(wn * 64 + f * 16 + l15) * 32 + quad * 8];
        }
#pragma unroll
        for (int fm = 0; fm < 4; ++fm)
#pragma unroll
            for (int fn = 0; fn < 4; ++fn)
                acc[fm][fn] = __builtin_amdgcn_mfma_f32_16x16x32_bf16(af[fm], bf[fn], acc[fm][fn], 0, 0, 0);
    }
#pragma unroll
    for (int fm = 0; fm < 4; ++fm) {
        int mbase = m0 + wm * 64 + fm * 16 + quad * 4;
#pragma unroll
        for (int fn = 0; fn < 4; ++fn) {
            int n = n0 + wn * 64 + fn * 16 + l15;
            float bv = bias[n];
#pragma unroll
            for (int r = 0; r < 4; ++r)
                out[(size_t)(mbase + r) * E_ + n] = acc[fm][fn][r] + bv;
        }
    }
}

// ======== colsum_k v5: TBLK=128, XCD-affine, exp2-folded.
// Writes Li2 = log2(e)/colsum so flash's outer exp is a single mul+v_exp. ========
__global__ __launch_bounds__(512, 2) void colsum_k(const unsigned short* __restrict__ Q,
                                                   const unsigned short* __restrict__ K,
                                                   float* __restrict__ invLcol) {
    __shared__ float part[8][64];
    const int tid = threadIdx.x;
    const int wave = tid >> 6, lane = tid & 63;
    const int quad = lane >> 4, l15 = lane & 15;
    const int tg = wave >> 2, sg = wave & 3;
    const int p = blockIdx.x;
    const int bh = (p & 7) + 8 * ((p >> 3) >> 4);   // head locked to XCD p%8
    const int t0 = ((p >> 3) & 15) * 128;
    const unsigned short* Qh = Q + (size_t)bh * S_ * D_;
    const unsigned short* Kh = K + (size_t)bh * S_ * D_;
    short8 kf[32];
#pragma unroll
    for (int kc = 0; kc < 8; ++kc)
#pragma unroll
        for (int fm = 0; fm < 4; ++fm)
            kf[kc * 4 + fm] = *(const short8*)&Kh[(size_t)(t0 + tg * 64 + fm * 16 + l15) * D_ + kc * 32 + quad * 8];
    float rl[4][4] = {};
    const unsigned short* Qw = Qh + (size_t)(sg * 16 + l15) * D_ + quad * 8;
    short8 qf[8];
#pragma unroll
    for (int kc = 0; kc < 8; ++kc) qf[kc] = *(const short8*)&Qw[kc * 32];
    for (int s0 = 0; s0 < S_; s0 += 64) {
        f32x4 acc[4] = {};
#pragma unroll
        for (int kc = 0; kc < 8; ++kc)
#pragma unroll
            for (int fm = 0; fm < 4; ++fm)
                acc[fm] = __builtin_amdgcn_mfma_f32_16x16x32_bf16(kf[kc * 4 + fm], qf[kc], acc[fm], 0, 0, 0);
        int sn = (s0 + 64) & (S_ - 1);
#pragma unroll
        for (int kc = 0; kc < 8; ++kc)
            qf[kc] = *(const short8*)&Qw[(size_t)sn * D_ + kc * 32];
#pragma unroll
        for (int fm = 0; fm < 4; ++fm)
#pragma unroll
            for (int r = 0; r < 4; ++r)
                rl[fm][r] += exp2f(acc[fm][r] * C1_);
    }
#pragma unroll
    for (int fm = 0; fm < 4; ++fm)
#pragma unroll
        for (int r = 0; r < 4; ++r) {
            float v = rl[fm][r];
            v += __shfl_xor(v, 1); v += __shfl_xor(v, 2);
            v += __shfl_xor(v, 4); v += __shfl_xor(v, 8);
            if (l15 == 0) part[wave][fm * 16 + quad * 4 + r] = v;
        }
    __syncthreads();
    if (tid < 128) {
        int tg2 = tid >> 6, i = tid & 63;
        float s = part[tg2 * 4 + 0][i] + part[tg2 * 4 + 1][i] +
                  part[tg2 * 4 + 2][i] + part[tg2 * 4 + 3][i];
        invLcol[(size_t)bh * S_ + t0 + tid] = LOG2E_ / s;
    }
}

// ======== flash13_k: flash12 + Q HOISTED TO REGISTERS + exp2 folding.
// Diagnosis (r8): 4000 cyc/chunk vs 670 of work — the 16 inline global Q loads
// per chunk serialize (allocator at 256-reg boundary can't keep them in flight).
// qreg[2][8] (64 VGPR, loaded once) replaces the transient load buffers: the
// chunk loop now has ZERO global loads (staging is fire-and-forget gl_lds).
// exp2: e = exp2(exp2(sc*C1)*Li2), C1/Li2 pre-folded (-2 VALU ops/elem).
// Budget: zacc 128 AGPR + qreg 64 + acc 16 + transients ~ 250. ========
__global__ __launch_bounds__(256, 2) void flash13_k(const unsigned short* __restrict__ Q,
                                                    const unsigned short* __restrict__ K,
                                                    const unsigned short* __restrict__ Vt,
                                                    const float* __restrict__ invLcol,
                                                    unsigned short* __restrict__ Zall) {
    __shared__ __align__(16) char KsB[2 * 16 * 1024];  // [buf][seg=kc*2+sub][lane*16]
    __shared__ __align__(16) char VsB[2 * 16 * 1024];  // [buf][dt][lane*16]
    const int tid = threadIdx.x;
    const int wave = tid >> 6, lane = tid & 63;
    const int q = lane >> 4, l15 = lane & 15;
    const int p = blockIdx.x;
    const int bh = (p & 7) + 8 * ((p >> 3) >> 4);   // head locked to XCD p%8
    const int s0 = ((p >> 3) & 15) * 128;
    const int bb = bh >> 3, hh = bh & 7;
    const unsigned short* Qh = Q + (size_t)bh * S_ * D_;
    const unsigned short* Kh = K + (size_t)bh * S_ * D_;
    const unsigned short* Vh = Vt + (size_t)bh * D_ * S_;
    const float* Lc = invLcol + (size_t)bh * S_;
    const int sbase = s0 + wave * 32;
    const int krow = 8 * (l15 >> 2) + (l15 & 3);

    // ---- hoist Q fragments (B-operand) into registers: 2 st x 8 kc = 64 VGPR ----
    const unsigned short* Qw0 = Qh + (size_t)(sbase + l15) * D_ + q * 8;
    const unsigned short* Qw1 = Qw0 + (size_t)16 * D_;
    short8 qreg0[8], qreg1[8];
#pragma unroll
    for (int kc = 0; kc < 8; ++kc) {
        qreg0[kc] = *(const short8*)&Qw0[kc * 32];
        qreg1[kc] = *(const short8*)&Qw1[kc * 32];
    }

    f32x4 zacc[2][16] = {};   // [st][dt] -> AGPRs
    float rsacc[2] = {0.f, 0.f};

#pragma unroll
    for (int i = 0; i < 4; ++i) {
        const int seg = wave * 4 + i;
        const int kc = seg >> 1, sub = seg & 1;
        gl_lds16(Kh + (size_t)(sub * 4 + krow) * D_ + kc * 32 + q * 8, KsB + seg * 1024);
        gl_lds16(Vh + (size_t)(seg * 16 + l15) * S_ + q * 8, VsB + seg * 1024);
    }
    __syncthreads();

    for (int c = 0; c < 64; ++c) {
        const int t0 = c * 32;
        const char* Kcur = KsB + (c & 1) * 16384;
        const char* Vcur = VsB + (c & 1) * 16384;
        if (c < 63) {
            const int tn = t0 + 32;
            char* Knxt = KsB + ((c & 1) ^ 1) * 16384;
            char* Vnxt = VsB + ((c & 1) ^ 1) * 16384;
#pragma unroll
            for (int i = 0; i < 4; ++i) {
                const int seg = wave * 4 + i;
                const int kc = seg >> 1, sub = seg & 1;
                gl_lds16(Kh + (size_t)(tn + sub * 4 + krow) * D_ + kc * 32 + q * 8, Knxt + seg * 1024);
                gl_lds16(Vh + (size_t)(seg * 16 + l15) * S_ + tn + q * 8, Vnxt + seg * 1024);
            }
        }
        // ---- QK (swapped): zero global loads; K from LDS, Q from regs ----
        f32x4 acc[2][2] = {};
#pragma unroll
        for (int kc = 0; kc < 8; ++kc) {
            short8 kf0 = *(const short8*)(Kcur + (kc * 2 + 0) * 1024 + lane * 16);
            short8 kf1 = *(const short8*)(Kcur + (kc * 2 + 1) * 1024 + lane * 16);
            acc[0][0] = __builtin_amdgcn_mfma_f32_16x16x32_bf16(kf0, qreg0[kc], acc[0][0], 0, 0, 0);
            acc[0][1] = __builtin_amdgcn_mfma_f32_16x16x32_bf16(kf1, qreg0[kc], acc[0][1], 0, 0, 0);
            acc[1][0] = __builtin_amdgcn_mfma_f32_16x16x32_bf16(kf0, qreg1[kc], acc[1][0], 0, 0, 0);
            acc[1][1] = __builtin_amdgcn_mfma_f32_16x16x32_bf16(kf1, qreg1[kc], acc[1][1], 0, 0, 0);
        }
        // ---- P = exp2(exp2(sc*C1)*Li2), lane-local pack ----
        const float4 iv0 = *(const float4*)(Lc + t0 + 8 * q);
        const float4 iv1 = *(const float4*)(Lc + t0 + 8 * q + 4);
        short8 pa[2];
#pragma unroll
        for (int st = 0; st < 2; ++st) {
            const f32x4 a0 = acc[st][0], a1 = acc[st][1];
            float e0 = exp2f(exp2f(a0[0] * C1_) * iv0.x);
            float e1 = exp2f(exp2f(a0[1] * C1_) * iv0.y);
            float e2 = exp2f(exp2f(a0[2] * C1_) * iv0.z);
            float e3 = exp2f(exp2f(a0[3] * C1_) * iv0.w);
            float e4 = exp2f(exp2f(a1[0] * C1_) * iv1.x);
            float e5 = exp2f(exp2f(a1[1] * C1_) * iv1.y);
            float e6 = exp2f(exp2f(a1[2] * C1_) * iv1.z);
            float e7 = exp2f(exp2f(a1[3] * C1_) * iv1.w);
            rsacc[st] += ((e0 + e1) + (e2 + e3)) + ((e4 + e5) + (e6 + e7));
            union { short8 v; unsigned u[4]; } P;
            P.u[0] = pk2(e0, e1);
            P.u[1] = pk2(e2, e3);
            P.u[2] = pk2(e4, e5);
            P.u[3] = pk2(e6, e7);
            pa[st] = P.v;
        }
        // ---- PV ----
#pragma unroll
        for (int dt = 0; dt < 16; ++dt) {
            short8 vb = *(const short8*)(Vcur + dt * 1024 + lane * 16);
            zacc[0][dt] = __builtin_amdgcn_mfma_f32_16x16x32_bf16(pa[0], vb, zacc[0][dt], 0, 0, 0);
            zacc[1][dt] = __builtin_amdgcn_mfma_f32_16x16x32_bf16(pa[1], vb, zacc[1][dt], 0, 0, 0);
        }
        __syncthreads();
    }
#pragma unroll
    for (int st = 0; st < 2; ++st) {
        float rs = rsacc[st];
        rs += __shfl_xor(rs, 16);
        rs += __shfl_xor(rs, 32);
#pragma unroll
        for (int r = 0; r < 4; ++r) {
            const float inv = 1.0f / __shfl(rs, q * 4 + r);
            const size_t rowoff = (size_t)(bb * S_ + sbase + st * 16 + q * 4 + r) * HD_ + hh * D_;
#pragma unroll
            for (int dt = 0; dt < 16; ++dt)
                Zall[rowoff + dt * 16 + l15] = f2bf(zacc[st][dt][r] * inv);
        }
    }
}

extern "C" void kernel_launch(void* const* d_in, const int* in_sizes, int n_in,
                              void* d_out, int out_size, void* d_ws, size_t ws_size,
                              hipStream_t stream) {
    const float* Ain = (const float*)d_in[0];
    const float* WQ = (const float*)d_in[1];
    const float* bQ = (const float*)d_in[2];
    const float* WK = (const float*)d_in[3];
    const float* bK = (const float*)d_in[4];
    const float* WV = (const float*)d_in[5];
    const float* bV = (const float*)d_in[6];
    const float* WZ = (const float*)d_in[7];
    const float* bZ = (const float*)d_in[8];
    float* out = (float*)d_out;

    char* ws = (char*)d_ws;
    size_t off = 0;
    auto alloc = [&](size_t bytes) {
        char* p = ws + off;
        off += (bytes + 255) & ~(size_t)255;
        return p;
    };
    unsigned short* Abf = (unsigned short*)alloc((size_t)BS_ * E_ * 2);
    unsigned short* Wqt = (unsigned short*)alloc((size_t)H_ * D_ * E_ * 2);
    unsigned short* Wkt = (unsigned short*)alloc((size_t)H_ * D_ * E_ * 2);
    unsigned short* Wvt = (unsigned short*)alloc((size_t)H_ * D_ * E_ * 2);
    unsigned short* Wzt = (unsigned short*)alloc((size_t)E_ * HD_ * 2);
    unsigned short* Qb = (unsigned short*)alloc((size_t)BH_ * S_ * D_ * 2);
    unsigned short* Kb = (unsigned short*)alloc((size_t)BH_ * S_ * D_ * 2);
    unsigned short* Vb = (unsigned short*)alloc((size_t)BH_ * S_ * D_ * 2);
    unsigned short* Vtb = (unsigned short*)alloc((size_t)BH_ * S_ * D_ * 2);
    unsigned short* Zb = (unsigned short*)alloc((size_t)BS_ * HD_ * 2);
    float* Lc = (float*)alloc((size_t)BH_ * S_ * 4);

    dim3 tb(32, 8);
    cast_k<<<(BS_ * E_ / 4 + 255) / 256, 256, 0, stream>>>(Ain, Abf, BS_ * E_ / 4);
    tcast_k<<<dim3(D_ / 32, E_ / 32, H_), tb, 0, stream>>>(WQ, Wqt, E_, D_);
    tcast_k<<<dim3(D_ / 32, E_ / 32, H_), tb, 0, stream>>>(WK, Wkt, E_, D_);
    tcast_k<<<dim3(D_ / 32, E_ / 32, H_), tb, 0, stream>>>(WV, Wvt, E_, D_);
    tcast_k<<<dim3(E_ / 32, HD_ / 32, 1), tb, 0, stream>>>(WZ, Wzt, HD_, E_);

    gemm_qkv256_k<<<dim3((BS_ / 256) * (HD_ / 256)), 512, 0, stream>>>(Abf, Wqt, bQ, Qb);
    gemm_qkv256_k<<<dim3((BS_ / 256) * (HD_ / 256)), 512, 0, stream>>>(Abf, Wkt, bK, Kb);
    gemm_qkv256_k<<<dim3((BS_ / 256) * (HD_ / 256)), 512, 0, stream>>>(Abf, Wvt, bV, Vb);

    tbf_k<<<dim3(D_ / 32, S_ / 32, BH_), tb, 0, stream>>>(Vb, Vtb);

    colsum_k<<<dim3(BH_ * S_ / 128), 512, 0, stream>>>(Qb, Kb, Lc);
    flash13_k<<<dim3(BH_ * S_ / 128), 256, 0, stream>>>(Qb, Kb, Vtb, Lc, Zb);

    gemm_out_k<<<dim3(E_ / 128, BS_ / 128), 256, 0, stream>>>(Zb, Wzt, bZ, out);
}

// Round 10
// 639.648 us; speedup vs baseline: 1.0032x; 1.0032x over previous
//
#include <hip/hip_runtime.h>

typedef __attribute__((ext_vector_type(8))) short short8;
typedef __attribute__((ext_vector_type(4))) float f32x4;

constexpr int B_ = 4, S_ = 2048, E_ = 1024, H_ = 8, D_ = 256;
constexpr int HD_ = H_ * D_;   // 2048
constexpr int BS_ = B_ * S_;   // 8192
constexpr int BH_ = B_ * H_;   // 32
constexpr float C1_ = 0.04508422002778011f;  // log2(e)/sqrt(1024)
constexpr float LOG2E_ = 1.4426950408889634f;

__device__ __forceinline__ unsigned short f2bf(float f) {
    union { float f; unsigned u; } x; x.f = f;
    unsigned r = (x.u + 0x7fffu + ((x.u >> 16) & 1u)) >> 16;
    return (unsigned short)r;
}

__device__ __forceinline__ void gl_lds16(const void* g, void* lds) {
    __builtin_amdgcn_global_load_lds((const __attribute__((address_space(1))) void*)g,
                                     (__attribute__((address_space(3))) void*)lds, 16, 0, 0);
}

// ---------------- cast A fp32 -> bf16 (vectorized) ----------------
__global__ __launch_bounds__(256) void cast_k(const float* __restrict__ src,
                                              unsigned short* __restrict__ dst, int n4) {
    int i = blockIdx.x * 256 + threadIdx.x;
    if (i >= n4) return;
    float4 v = reinterpret_cast<const float4*>(src)[i];
    ushort4 o;
    o.x = f2bf(v.x); o.y = f2bf(v.y); o.z = f2bf(v.z); o.w = f2bf(v.w);
    reinterpret_cast<ushort4*>(dst)[i] = o;
}

// ------------- batched transpose+cast: (bt,R,C) f32 -> (bt,C,R) bf16 -------------
__global__ __launch_bounds__(256) void tcast_k(const float* __restrict__ src,
                                               unsigned short* __restrict__ dst, int R, int C) {
    __shared__ float tile[32][33];
    int b = blockIdx.z;
    const float* s = src + (size_t)b * R * C;
    unsigned short* d = dst + (size_t)b * R * C;
    int c0 = blockIdx.x * 32, r0 = blockIdx.y * 32;
    int tx = threadIdx.x, ty = threadIdx.y;
#pragma unroll
    for (int i = 0; i < 4; ++i)
        tile[ty + i * 8][tx] = s[(size_t)(r0 + ty + i * 8) * C + c0 + tx];
    __syncthreads();
#pragma unroll
    for (int i = 0; i < 4; ++i)
        d[(size_t)(c0 + ty + i * 8) * R + r0 + tx] = f2bf(tile[tx][ty + i * 8]);
}

// ------------- bf16 transpose: (BH,S,D) -> (BH,D,S) -------------
__global__ __launch_bounds__(256) void tbf_k(const unsigned short* __restrict__ src,
                                             unsigned short* __restrict__ dst) {
    __shared__ unsigned short tile[32][33];
    int bh = blockIdx.z;
    int d0 = blockIdx.x * 32, s0 = blockIdx.y * 32;
    int tx = threadIdx.x, ty = threadIdx.y;
#pragma unroll
    for (int i = 0; i < 4; ++i)
        tile[ty + i * 8][tx] = src[((size_t)bh * S_ + s0 + ty + i * 8) * D_ + d0 + tx];
    __syncthreads();
#pragma unroll
    for (int i = 0; i < 4; ++i)
        dst[((size_t)bh * D_ + d0 + ty + i * 8) * S_ + s0 + tx] = tile[tx][ty + i * 8];
}

// ======== gemm_qkv256_k: 256x256 tile, BK=64, 2-phase single-barrier pipeline.
// (r8-proven) ========
__global__ __launch_bounds__(512, 2) void gemm_qkv256_k(const unsigned short* __restrict__ A,
                                                        const unsigned short* __restrict__ Bt,
                                                        const float* __restrict__ bias,
                                                        unsigned short* __restrict__ out) {
    __shared__ __align__(16) unsigned short As[2][256 * 64];  // 64 KB
    __shared__ __align__(16) unsigned short Bs[2][256 * 64];  // 64 KB
    const int tid = threadIdx.x;
    const int wave = tid >> 6, lane = tid & 63;
    const int quad = lane >> 4, l15 = lane & 15;
    const int wm = wave >> 2, wn = wave & 3;
    const int lrow = lane >> 3, lc = lane & 7;
    const int p = blockIdx.x;
    const int n0 = (p & 7) * 256;          // XCD-locked B panel
    const int m0 = (p >> 3) * 256;
    int aoff[4], boff[4];
#pragma unroll
    for (int i = 0; i < 4; ++i) {
        int rA = m0 + (wave * 4 + i) * 8 + lrow;
        int rB = n0 + (wave * 4 + i) * 8 + lrow;
        aoff[i] = rA * E_ + (lc ^ lrow) * 8;
        boff[i] = rB * E_ + (lc ^ lrow) * 8;
    }
    f32x4 acc[8][4] = {};
#pragma unroll
    for (int i = 0; i < 4; ++i) {
        gl_lds16(A + aoff[i], (char*)As + (wave * 4 + i) * 1024);
        gl_lds16(Bt + boff[i], (char*)Bs + (wave * 4 + i) * 1024);
    }
    __syncthreads();
    const int v0 = (quad ^ (l15 & 7)) * 16;
    const int arow = (wm * 128 + l15) * 128;
    const int brow = (wn * 64 + l15) * 128;
    for (int k0 = 0; k0 < E_; k0 += 64) {
        const int cur = (k0 >> 6) & 1;
        if (k0 + 64 < E_) {
            char* An = (char*)As + (cur ^ 1) * 32768;
            char* Bn = (char*)Bs + (cur ^ 1) * 32768;
#pragma unroll
            for (int i = 0; i < 4; ++i) {
                gl_lds16(A + aoff[i] + k0 + 64, An + (wave * 4 + i) * 1024);
                gl_lds16(Bt + boff[i] + k0 + 64, Bn + (wave * 4 + i) * 1024);
            }
        }
        const char* Ac = (const char*)As + cur * 32768;
        const char* Bc = (const char*)Bs + cur * 32768;
#pragma unroll
        for (int kcc = 0; kcc < 2; ++kcc) {
            const int vk = v0 ^ (kcc << 6);
            short8 af[8], bf[4];
#pragma unroll
            for (int fm = 0; fm < 8; ++fm)
                af[fm] = *(const short8*)(Ac + arow + fm * 2048 + vk);
#pragma unroll
            for (int fn = 0; fn < 4; ++fn)
                bf[fn] = *(const short8*)(Bc + brow + fn * 2048 + vk);
#pragma unroll
            for (int fm = 0; fm < 8; ++fm)
#pragma unroll
                for (int fn = 0; fn < 4; ++fn)
                    acc[fm][fn] = __builtin_amdgcn_mfma_f32_16x16x32_bf16(af[fm], bf[fn], acc[fm][fn], 0, 0, 0);
        }
        __syncthreads();
    }
#pragma unroll
    for (int fm = 0; fm < 8; ++fm) {
        int mbase = m0 + wm * 128 + fm * 16 + quad * 4;
#pragma unroll
        for (int fn = 0; fn < 4; ++fn) {
            int n = n0 + wn * 64 + fn * 16 + l15;
            int h = n >> 8, d = n & 255;
            float bv = bias[n];
#pragma unroll
            for (int r = 0; r < 4; ++r) {
                int m = mbase + r;
                int b = m >> 11, s = m & 2047;
                float v = fmaxf(acc[fm][fn][r] + bv, 0.0f);
                out[((size_t)(b * H_ + h) * S_ + s) * D_ + d] = f2bf(v);
            }
        }
    }
}

// ======== gemm_out256_k: 256x128 tile, BK=64, same proven pipeline/swizzle.
// 8 waves (4M x 2N), per-wave 64x64 (acc 64 AGPR). Grid 256: n-panel locked
// to XCD (p&7, 128 cols x 2048 k = 512KB L2-resident), m0 = (p>>3)*256.
// K-loop over HD=2048 (32 steps). fp32 output + bias, no relu. ========
__global__ __launch_bounds__(512, 2) void gemm_out256_k(const unsigned short* __restrict__ A,
                                                        const unsigned short* __restrict__ Bt,
                                                        const float* __restrict__ bias,
                                                        float* __restrict__ out) {
    __shared__ __align__(16) unsigned short As[2][256 * 64];  // 64 KB
    __shared__ __align__(16) unsigned short Bs[2][128 * 64];  // 32 KB
    const int tid = threadIdx.x;
    const int wave = tid >> 6, lane = tid & 63;
    const int quad = lane >> 4, l15 = lane & 15;
    const int wm = wave >> 1, wn = wave & 1;   // 4M x 2N
    const int lrow = lane >> 3, lc = lane & 7;
    const int p = blockIdx.x;
    const int n0 = (p & 7) * 128;          // XCD-locked B panel
    const int m0 = (p >> 3) * 256;
    int aoff[4], boff[2];
#pragma unroll
    for (int i = 0; i < 4; ++i) {
        int rA = m0 + (wave * 4 + i) * 8 + lrow;
        aoff[i] = rA * HD_ + (lc ^ lrow) * 8;
    }
#pragma unroll
    for (int i = 0; i < 2; ++i) {
        int rB = n0 + (wave * 2 + i) * 8 + lrow;
        boff[i] = rB * HD_ + (lc ^ lrow) * 8;
    }
    f32x4 acc[4][4] = {};
#pragma unroll
    for (int i = 0; i < 4; ++i)
        gl_lds16(A + aoff[i], (char*)As + (wave * 4 + i) * 1024);
#pragma unroll
    for (int i = 0; i < 2; ++i)
        gl_lds16(Bt + boff[i], (char*)Bs + (wave * 2 + i) * 1024);
    __syncthreads();
    const int v0 = (quad ^ (l15 & 7)) * 16;
    const int arow = (wm * 64 + l15) * 128;
    const int brow = (wn * 64 + l15) * 128;
    for (int k0 = 0; k0 < HD_; k0 += 64) {
        const int cur = (k0 >> 6) & 1;
        if (k0 + 64 < HD_) {
            char* An = (char*)As + (cur ^ 1) * 32768;
            char* Bn = (char*)Bs + (cur ^ 1) * 16384;
#pragma unroll
            for (int i = 0; i < 4; ++i)
                gl_lds16(A + aoff[i] + k0 + 64, An + (wave * 4 + i) * 1024);
#pragma unroll
            for (int i = 0; i < 2; ++i)
                gl_lds16(Bt + boff[i] + k0 + 64, Bn + (wave * 2 + i) * 1024);
        }
        const char* Ac = (const char*)As + cur * 32768;
        const char* Bc = (const char*)Bs + cur * 16384;
#pragma unroll
        for (int kcc = 0; kcc < 2; ++kcc) {
            const int vk = v0 ^ (kcc << 6);
            short8 af[4], bf[4];
#pragma unroll
            for (int fm = 0; fm < 4; ++fm)
                af[fm] = *(const short8*)(Ac + arow + fm * 2048 + vk);
#pragma unroll
            for (int fn = 0; fn < 4; ++fn)
                bf[fn] = *(const short8*)(Bc + brow + fn * 2048 + vk);
#pragma unroll
            for (int fm = 0; fm < 4; ++fm)
#pragma unroll
                for (int fn = 0; fn < 4; ++fn)
                    acc[fm][fn] = __builtin_amdgcn_mfma_f32_16x16x32_bf16(af[fm], bf[fn], acc[fm][fn], 0, 0, 0);
        }
        __syncthreads();
    }
#pragma unroll
    for (int fm = 0; fm < 4; ++fm) {
        int mbase = m0 + wm * 64 + fm * 16 + quad * 4;
#pragma unroll
        for (int fn = 0; fn < 4; ++fn) {
            int n = n0 + wn * 64 + fn * 16 + l15;
            float bv = bias[n];
#pragma unroll
            for (int r = 0; r < 4; ++r)
                out[(size_t)(mbase + r) * E_ + n] = acc[fm][fn][r] + bv;
        }
    }
}

// ======== colsum_k v5: TBLK=128, XCD-affine, exp2-folded. (unchanged) ========
__global__ __launch_bounds__(512, 2) void colsum_k(const unsigned short* __restrict__ Q,
                                                   const unsigned short* __restrict__ K,
                                                   float* __restrict__ invLcol) {
    __shared__ float part[8][64];
    const int tid = threadIdx.x;
    const int wave = tid >> 6, lane = tid & 63;
    const int quad = lane >> 4, l15 = lane & 15;
    const int tg = wave >> 2, sg = wave & 3;
    const int p = blockIdx.x;
    const int bh = (p & 7) + 8 * ((p >> 3) >> 4);   // head locked to XCD p%8
    const int t0 = ((p >> 3) & 15) * 128;
    const unsigned short* Qh = Q + (size_t)bh * S_ * D_;
    const unsigned short* Kh = K + (size_t)bh * S_ * D_;
    short8 kf[32];
#pragma unroll
    for (int kc = 0; kc < 8; ++kc)
#pragma unroll
        for (int fm = 0; fm < 4; ++fm)
            kf[kc * 4 + fm] = *(const short8*)&Kh[(size_t)(t0 + tg * 64 + fm * 16 + l15) * D_ + kc * 32 + quad * 8];
    float rl[4][4] = {};
    const unsigned short* Qw = Qh + (size_t)(sg * 16 + l15) * D_ + quad * 8;
    short8 qf[8];
#pragma unroll
    for (int kc = 0; kc < 8; ++kc) qf[kc] = *(const short8*)&Qw[kc * 32];
    for (int s0 = 0; s0 < S_; s0 += 64) {
        f32x4 acc[4] = {};
#pragma unroll
        for (int kc = 0; kc < 8; ++kc)
#pragma unroll
            for (int fm = 0; fm < 4; ++fm)
                acc[fm] = __builtin_amdgcn_mfma_f32_16x16x32_bf16(kf[kc * 4 + fm], qf[kc], acc[fm], 0, 0, 0);
        int sn = (s0 + 64) & (S_ - 1);
#pragma unroll
        for (int kc = 0; kc < 8; ++kc)
            qf[kc] = *(const short8*)&Qw[(size_t)sn * D_ + kc * 32];
#pragma unroll
        for (int fm = 0; fm < 4; ++fm)
#pragma unroll
            for (int r = 0; r < 4; ++r)
                rl[fm][r] += exp2f(acc[fm][r] * C1_);
    }
#pragma unroll
    for (int fm = 0; fm < 4; ++fm)
#pragma unroll
        for (int r = 0; r < 4; ++r) {
            float v = rl[fm][r];
            v += __shfl_xor(v, 1); v += __shfl_xor(v, 2);
            v += __shfl_xor(v, 4); v += __shfl_xor(v, 8);
            if (l15 == 0) part[wave][fm * 16 + quad * 4 + r] = v;
        }
    __syncthreads();
    if (tid < 128) {
        int tg2 = tid >> 6, i = tid & 63;
        float s = part[tg2 * 4 + 0][i] + part[tg2 * 4 + 1][i] +
                  part[tg2 * 4 + 2][i] + part[tg2 * 4 + 3][i];
        invLcol[(size_t)bh * S_ + t0 + tid] = LOG2E_ / s;
    }
}

// ======== flash14_k: flash13 + hardware v_cvt_pk_bf16_f32 P-pack.
// r9 diagnosis: LDS-pipe ~90% utilized (8.4GB reads / 219us vs 52TB/s b128
// ceiling) — structural floor for this dataflow. VALUBusy 43% is the other
// contender; cvt_pk cuts ~70 VALU insts/chunk from the serial chain
// (software f2bf+or ~10 ops/pair -> 1 op/pair, RNE rounding identical). ========
__global__ __launch_bounds__(256, 2) void flash14_k(const unsigned short* __restrict__ Q,
                                                    const unsigned short* __restrict__ K,
                                                    const unsigned short* __restrict__ Vt,
                                                    const float* __restrict__ invLcol,
                                                    unsigned short* __restrict__ Zall) {
    __shared__ __align__(16) char KsB[2 * 16 * 1024];  // [buf][seg=kc*2+sub][lane*16]
    __shared__ __align__(16) char VsB[2 * 16 * 1024];  // [buf][dt][lane*16]
    const int tid = threadIdx.x;
    const int wave = tid >> 6, lane = tid & 63;
    const int q = lane >> 4, l15 = lane & 15;
    const int p = blockIdx.x;
    const int bh = (p & 7) + 8 * ((p >> 3) >> 4);   // head locked to XCD p%8
    const int s0 = ((p >> 3) & 15) * 128;
    const int bb = bh >> 3, hh = bh & 7;
    const unsigned short* Qh = Q + (size_t)bh * S_ * D_;
    const unsigned short* Kh = K + (size_t)bh * S_ * D_;
    const unsigned short* Vh = Vt + (size_t)bh * D_ * S_;
    const float* Lc = invLcol + (size_t)bh * S_;
    const int sbase = s0 + wave * 32;
    const int krow = 8 * (l15 >> 2) + (l15 & 3);

    const unsigned short* Qw0 = Qh + (size_t)(sbase + l15) * D_ + q * 8;
    const unsigned short* Qw1 = Qw0 + (size_t)16 * D_;
    short8 qreg0[8], qreg1[8];
#pragma unroll
    for (int kc = 0; kc < 8; ++kc) {
        qreg0[kc] = *(const short8*)&Qw0[kc * 32];
        qreg1[kc] = *(const short8*)&Qw1[kc * 32];
    }

    f32x4 zacc[2][16] = {};   // [st][dt] -> AGPRs
    float rsacc[2] = {0.f, 0.f};

#pragma unroll
    for (int i = 0; i < 4; ++i) {
        const int seg = wave * 4 + i;
        const int kc = seg >> 1, sub = seg & 1;
        gl_lds16(Kh + (size_t)(sub * 4 + krow) * D_ + kc * 32 + q * 8, KsB + seg * 1024);
        gl_lds16(Vh + (size_t)(seg * 16 + l15) * S_ + q * 8, VsB + seg * 1024);
    }
    __syncthreads();

    for (int c = 0; c < 64; ++c) {
        const int t0 = c * 32;
        const char* Kcur = KsB + (c & 1) * 16384;
        const char* Vcur = VsB + (c & 1) * 16384;
        if (c < 63) {
            const int tn = t0 + 32;
            char* Knxt = KsB + ((c & 1) ^ 1) * 16384;
            char* Vnxt = VsB + ((c & 1) ^ 1) * 16384;
#pragma unroll
            for (int i = 0; i < 4; ++i) {
                const int seg = wave * 4 + i;
                const int kc = seg >> 1, sub = seg & 1;
                gl_lds16(Kh + (size_t)(tn + sub * 4 + krow) * D_ + kc * 32 + q * 8, Knxt + seg * 1024);
                gl_lds16(Vh + (size_t)(seg * 16 + l15) * S_ + tn + q * 8, Vnxt + seg * 1024);
            }
        }
        // ---- QK (swapped): K from LDS, Q from regs ----
        f32x4 acc[2][2] = {};
#pragma unroll
        for (int kc = 0; kc < 8; ++kc) {
            short8 kf0 = *(const short8*)(Kcur + (kc * 2 + 0) * 1024 + lane * 16);
            short8 kf1 = *(const short8*)(Kcur + (kc * 2 + 1) * 1024 + lane * 16);
            acc[0][0] = __builtin_amdgcn_mfma_f32_16x16x32_bf16(kf0, qreg0[kc], acc[0][0], 0, 0, 0);
            acc[0][1] = __builtin_amdgcn_mfma_f32_16x16x32_bf16(kf1, qreg0[kc], acc[0][1], 0, 0, 0);
            acc[1][0] = __builtin_amdgcn_mfma_f32_16x16x32_bf16(kf0, qreg1[kc], acc[1][0], 0, 0, 0);
            acc[1][1] = __builtin_amdgcn_mfma_f32_16x16x32_bf16(kf1, qreg1[kc], acc[1][1], 0, 0, 0);
        }
        // ---- P = exp2(exp2(sc*C1)*Li2), lane-local; hw cvt_pk pack ----
        const float4 iv0 = *(const float4*)(Lc + t0 + 8 * q);
        const float4 iv1 = *(const float4*)(Lc + t0 + 8 * q + 4);
        short8 pa[2];
#pragma unroll
        for (int st = 0; st < 2; ++st) {
            const f32x4 a0 = acc[st][0], a1 = acc[st][1];
            float e0 = exp2f(exp2f(a0[0] * C1_) * iv0.x);
            float e1 = exp2f(exp2f(a0[1] * C1_) * iv0.y);
            float e2 = exp2f(exp2f(a0[2] * C1_) * iv0.z);
            float e3 = exp2f(exp2f(a0[3] * C1_) * iv0.w);
            float e4 = exp2f(exp2f(a1[0] * C1_) * iv1.x);
            float e5 = exp2f(exp2f(a1[1] * C1_) * iv1.y);
            float e6 = exp2f(exp2f(a1[2] * C1_) * iv1.z);
            float e7 = exp2f(exp2f(a1[3] * C1_) * iv1.w);
            rsacc[st] += ((e0 + e1) + (e2 + e3)) + ((e4 + e5) + (e6 + e7));
            union { short8 v; unsigned u[4]; } P;
            asm("v_cvt_pk_bf16_f32 %0, %1, %2" : "=v"(P.u[0]) : "v"(e0), "v"(e1));
            asm("v_cvt_pk_bf16_f32 %0, %1, %2" : "=v"(P.u[1]) : "v"(e2), "v"(e3));
            asm("v_cvt_pk_bf16_f32 %0, %1, %2" : "=v"(P.u[2]) : "v"(e4), "v"(e5));
            asm("v_cvt_pk_bf16_f32 %0, %1, %2" : "=v"(P.u[3]) : "v"(e6), "v"(e7));
            pa[st] = P.v;
        }
        // ---- PV ----
#pragma unroll
        for (int dt = 0; dt < 16; ++dt) {
            short8 vb = *(const short8*)(Vcur + dt * 1024 + lane * 16);
            zacc[0][dt] = __builtin_amdgcn_mfma_f32_16x16x32_bf16(pa[0], vb, zacc[0][dt], 0, 0, 0);
            zacc[1][dt] = __builtin_amdgcn_mfma_f32_16x16x32_bf16(pa[1], vb, zacc[1][dt], 0, 0, 0);
        }
        __syncthreads();
    }
#pragma unroll
    for (int st = 0; st < 2; ++st) {
        float rs = rsacc[st];
        rs += __shfl_xor(rs, 16);
        rs += __shfl_xor(rs, 32);
#pragma unroll
        for (int r = 0; r < 4; ++r) {
            const float inv = 1.0f / __shfl(rs, q * 4 + r);
            const size_t rowoff = (size_t)(bb * S_ + sbase + st * 16 + q * 4 + r) * HD_ + hh * D_;
#pragma unroll
            for (int dt = 0; dt < 16; ++dt)
                Zall[rowoff + dt * 16 + l15] = f2bf(zacc[st][dt][r] * inv);
        }
    }
}

extern "C" void kernel_launch(void* const* d_in, const int* in_sizes, int n_in,
                              void* d_out, int out_size, void* d_ws, size_t ws_size,
                              hipStream_t stream) {
    const float* Ain = (const float*)d_in[0];
    const float* WQ = (const float*)d_in[1];
    const float* bQ = (const float*)d_in[2];
    const float* WK = (const float*)d_in[3];
    const float* bK = (const float*)d_in[4];
    const float* WV = (const float*)d_in[5];
    const float* bV = (const float*)d_in[6];
    const float* WZ = (const float*)d_in[7];
    const float* bZ = (const float*)d_in[8];
    float* out = (float*)d_out;

    char* ws = (char*)d_ws;
    size_t off = 0;
    auto alloc = [&](size_t bytes) {
        char* p = ws + off;
        off += (bytes + 255) & ~(size_t)255;
        return p;
    };
    unsigned short* Abf = (unsigned short*)alloc((size_t)BS_ * E_ * 2);
    unsigned short* Wqt = (unsigned short*)alloc((size_t)H_ * D_ * E_ * 2);
    unsigned short* Wkt = (unsigned short*)alloc((size_t)H_ * D_ * E_ * 2);
    unsigned short* Wvt = (unsigned short*)alloc((size_t)H_ * D_ * E_ * 2);
    unsigned short* Wzt = (unsigned short*)alloc((size_t)E_ * HD_ * 2);
    unsigned short* Qb = (unsigned short*)alloc((size_t)BH_ * S_ * D_ * 2);
    unsigned short* Kb = (unsigned short*)alloc((size_t)BH_ * S_ * D_ * 2);
    unsigned short* Vb = (unsigned short*)alloc((size_t)BH_ * S_ * D_ * 2);
    unsigned short* Vtb = (unsigned short*)alloc((size_t)BH_ * S_ * D_ * 2);
    unsigned short* Zb = (unsigned short*)alloc((size_t)BS_ * HD_ * 2);
    float* Lc = (float*)alloc((size_t)BH_ * S_ * 4);

    dim3 tb(32, 8);
    cast_k<<<(BS_ * E_ / 4 + 255) / 256, 256, 0, stream>>>(Ain, Abf, BS_ * E_ / 4);
    tcast_k<<<dim3(D_ / 32, E_ / 32, H_), tb, 0, stream>>>(WQ, Wqt, E_, D_);
    tcast_k<<<dim3(D_ / 32, E_ / 32, H_), tb, 0, stream>>>(WK, Wkt, E_, D_);
    tcast_k<<<dim3(D_ / 32, E_ / 32, H_), tb, 0, stream>>>(WV, Wvt, E_, D_);
    tcast_k<<<dim3(E_ / 32, HD_ / 32, 1), tb, 0, stream>>>(WZ, Wzt, HD_, E_);

    gemm_qkv256_k<<<dim3((BS_ / 256) * (HD_ / 256)), 512, 0, stream>>>(Abf, Wqt, bQ, Qb);
    gemm_qkv256_k<<<dim3((BS_ / 256) * (HD_ / 256)), 512, 0, stream>>>(Abf, Wkt, bK, Kb);
    gemm_qkv256_k<<<dim3((BS_ / 256) * (HD_ / 256)), 512, 0, stream>>>(Abf, Wvt, bV, Vb);

    tbf_k<<<dim3(D_ / 32, S_ / 32, BH_), tb, 0, stream>>>(Vb, Vtb);

    colsum_k<<<dim3(BH_ * S_ / 128), 512, 0, stream>>>(Qb, Kb, Lc);
    flash14_k<<<dim3(BH_ * S_ / 128), 256, 0, stream>>>(Qb, Kb, Vtb, Lc, Zb);

    gemm_out256_k<<<dim3((BS_ / 256) * (E_ / 128)), 512, 0, stream>>>(Zb, Wzt, bZ, out);
}